// Round 15
// baseline (244.856 us; speedup 1.0000x reference)
//
#include <hip/hip_runtime.h>
#include <hip/hip_bf16.h>

#define NB 8192
#define ND 256
#define NKBP 63
#define NF 64
#define NE 64
#define NKP 16384   // D*F
#define NDE 16384   // D*E
#define NSPLIT 4    // split-K factor for k_proj (64 d per block)

typedef __attribute__((ext_vector_type(8))) short short8_t;
typedef __attribute__((ext_vector_type(4))) short short4_t;
typedef __attribute__((ext_vector_type(4))) float f32x4;

__device__ __forceinline__ unsigned short bfbits(float v) {
  union { __hip_bfloat16 b; unsigned short u; } cv;
  cv.b = __float2bfloat16(v);
  return cv.u;
}
__device__ __forceinline__ float bf2f(unsigned short s) {
  return __uint_as_float(((unsigned)s) << 16);
}

// ---------------- K0 (fused): per-block max of x + bwT fragment-native prep ----------------
__global__ void k_mp(const float* __restrict__ x, const float* __restrict__ bw,
                     float* __restrict__ bmax, unsigned short* __restrict__ bwT) {
  const int t = threadIdx.x;
  const float* px = x + (size_t)blockIdx.x * 8192;
  float m = 0.f;  // clamped at 0: conservative (only ever raises Fd)
  #pragma unroll 4
  for (int i = t; i < 8192; i += 256) m = fmaxf(m, px[i]);
  #pragma unroll
  for (int off = 32; off > 0; off >>= 1) m = fmaxf(m, __shfl_down(m, off, 64));
  __shared__ float red[4];
  if ((t & 63) == 0) red[t >> 6] = m;
  __syncthreads();
  if (t == 0) bmax[blockIdx.x] = fmaxf(fmaxf(red[0], red[1]), fmaxf(red[2], red[3]));
  // bwT prep for d = blockIdx.x: elem (d,e,f) at bwT[(((d*2+kf)*4+lg)*64+e)*8+j]
  const int d = blockIdx.x;
  const int f = t >> 2, e0 = (t & 3) * 16;
  const int kf = f >> 5, lg = (f >> 3) & 3, j = f & 7;
  const size_t base = ((((size_t)d * 2 + kf) * 4 + lg) * 64) * 8 + j;
  #pragma unroll
  for (int q = 0; q < 4; ++q) {
    f32x4 v = *(const f32x4*)(bw + (size_t)d * 4096 + f * 64 + e0 + q * 4);
    #pragma unroll
    for (int r = 0; r < 4; ++r)
      bwT[base + (size_t)(e0 + q * 4 + r) * 8] = bfbits(v[r]);
  }
}

// ---------------- K0b (fallback when !FAST): plain maxx ----------------
__global__ void k_maxx(const float* __restrict__ x, float* __restrict__ bmax) {
  const int t = threadIdx.x;
  const float* px = x + (size_t)blockIdx.x * 8192;
  float m = 0.f;
  #pragma unroll 4
  for (int i = t; i < 8192; i += 256) m = fmaxf(m, px[i]);
  #pragma unroll
  for (int off = 32; off > 0; off >>= 1) m = fmaxf(m, __shfl_down(m, off, 64));
  __shared__ float red[4];
  if ((t & 63) == 0) red[t >> 6] = m;
  __syncthreads();
  if (t == 0) bmax[blockIdx.x] = fmaxf(fmaxf(red[0], red[1]), fmaxf(red[2], red[3]));
}

// ---------------- K1: breakpoints + effective-K flags + threshold table ----------------
__global__ void k_bp(const float* __restrict__ bmin, const float* __restrict__ draw,
                     const float* __restrict__ bmax, float* __restrict__ obp,
                     int* __restrict__ fdv, int* __restrict__ fcutc,
                     float* __restrict__ thrT) {
  const int d = threadIdx.x;  // 256 threads, one per d
  __shared__ float drawS[ND * NKBP];   // 63 KB, coalesced stage
  __shared__ float mred[256];
  __shared__ int fds[256];
  mred[d] = bmax[d];
  for (int i = d; i < ND * NKBP; i += 256) drawS[i] = draw[i];
  __syncthreads();
  for (int s = 128; s > 0; s >>= 1) {
    if (d < s) mred[d] = fmaxf(mred[d], mred[d + s]);
    __syncthreads();
  }
  const float maxx = mred[0];
  float a = bmin[d];
  int cnt = 0;
  if (thrT) thrT[d * 64] = 0.0f;
  for (int j = 0; j < NKBP; ++j) {
    float r = drawS[d * NKBP + j];
    a += fmaxf(r, 0.f) + log1pf(expf(-fabsf(r)));
    obp[d * NKBP + j] = a;
    if (thrT) thrT[d * 64 + 1 + j] = a;
    cnt += (a < maxx) ? 1 : 0;
  }
  const int Fd = 1 + cnt;
  fdv[d] = Fd;
  fds[d] = Fd;
  __syncthreads();
  if (d < NSPLIT) {
    int mx = 0;
    for (int k = 0; k < 64; ++k) mx = max(mx, fds[d * 64 + k]);
    fcutc[d] = (mx > 32) ? 2 : 1;
  }
}

// ---------------- K2: W2 (fragment-native blocked layout) + cbias partials ----------------
__global__ __launch_bounds__(256, 2) void k_w2(
    const float* __restrict__ bw, const float* __restrict__ pw,
    const float* __restrict__ bb, const int* __restrict__ fcutc,
    unsigned short* __restrict__ w2f, float* __restrict__ cb_part) {
  const int d = blockIdx.x;
  const int t = threadIdx.x;
  const int l = t & 63, w = t >> 6;
  const int lr = l & 15, lg = l >> 4;
  const int nkf = fcutc[d >> 6];   // 1 or 2
  __shared__ unsigned short pwS[256 * 72];
  __shared__ unsigned short bwS[64 * 72];
  __shared__ float bbS[64];

  {
    const int rr = t >> 4, e0 = (t & 15) * 4;
    #pragma unroll
    for (int it = 0; it < 16; ++it) {
      const int n = it * 16 + rr;
      f32x4 v = *(const f32x4*)(pw + (size_t)n * NDE + d * 64 + e0);
      short4_t s;
      s[0] = (short)bfbits(v[0]); s[1] = (short)bfbits(v[1]);
      s[2] = (short)bfbits(v[2]); s[3] = (short)bfbits(v[3]);
      *(short4_t*)(pwS + n * 72 + e0) = s;
    }
    const int itmax = (nkf == 2) ? 4 : 2;
    for (int it = 0; it < itmax; ++it) {
      const int f = it * 16 + rr;
      f32x4 v = *(const f32x4*)(bw + (size_t)d * 4096 + f * 64 + e0);
      short4_t s;
      s[0] = (short)bfbits(v[0]); s[1] = (short)bfbits(v[1]);
      s[2] = (short)bfbits(v[2]); s[3] = (short)bfbits(v[3]);
      *(short4_t*)(bwS + f * 72 + e0) = s;
    }
    if (t < 64) bbS[t] = bb[(size_t)d * 64 + t];
  }
  __syncthreads();

  f32x4 acc[4][4];
  #pragma unroll
  for (int mi = 0; mi < 4; ++mi)
    #pragma unroll
    for (int ni = 0; ni < 4; ++ni) acc[mi][ni] = (f32x4){0.f, 0.f, 0.f, 0.f};

  const int nimax = (nkf == 2) ? 4 : 2;
  for (int kf = 0; kf < nkf; ++kf) {
    short8_t afr[4], bfr[4];
    #pragma unroll
    for (int mi = 0; mi < 4; ++mi) {
      const int n = w * 64 + mi * 16 + lr;
      afr[mi] = *(const short8_t*)(pwS + n * 72 + kf * 32 + lg * 8);
    }
    for (int ni = 0; ni < nimax; ++ni) {
      const int f = ni * 16 + lr;
      bfr[ni] = *(const short8_t*)(bwS + f * 72 + kf * 32 + lg * 8);
    }
    for (int ni = 0; ni < nimax; ++ni)
      #pragma unroll
      for (int mi = 0; mi < 4; ++mi)
        acc[mi][ni] = __builtin_amdgcn_mfma_f32_16x16x32_bf16(afr[mi], bfr[ni], acc[mi][ni], 0, 0, 0);
  }

  #pragma unroll
  for (int mi = 0; mi < 4; ++mi)
    for (int ni = 0; ni < nimax; ++ni) {
      const int kf_s = ni >> 1;
      const int lgp  = (ni * 2 + (lr >> 3)) & 3;
      const int jj   = lr & 7;
      const int nb   = w * 64 + mi * 16 + lg * 4;
      const size_t base = (((size_t)d * 2 + kf_s) * 4 + lgp) * 256;
      #pragma unroll
      for (int r = 0; r < 4; ++r)
        w2f[(base + (nb + r)) * 8 + jj] = bfbits(acc[mi][ni][r]);
    }

  {
    float cacc = 0.f;
    #pragma unroll 8
    for (int e = 0; e < 64; ++e) cacc += bf2f(pwS[t * 72 + e]) * bbS[e];
    cb_part[(size_t)d * 256 + t] = cacc;
  }
}

// ---------------- K2r: cbias[n] = sum_d cb_part[d][n] ----------------
__global__ void k_cbr(const float* __restrict__ cb_part, float* __restrict__ c) {
  const int t = threadIdx.x;
  float a0 = 0.f, a1 = 0.f, a2 = 0.f, a3 = 0.f;
  for (int d = 0; d < ND; d += 4) {
    a0 += cb_part[(size_t)(d + 0) * 256 + t];
    a1 += cb_part[(size_t)(d + 1) * 256 + t];
    a2 += cb_part[(size_t)(d + 2) * 256 + t];
    a3 += cb_part[(size_t)(d + 3) * 256 + t];
  }
  c[t] = (a0 + a1) + (a2 + a3);
}

// ---------------- K3: projection GEMM partials; tile-major pbuf + LDS-staged 1KB-burst stores ----------------
template<bool KF1>
__device__ __forceinline__ void proj_kloop(
    const unsigned short* const (&bbase)[4], const float* const (&xrow)[2],
    const float* thrS_lg, bool lg0, f32x4 (&acc)[2][4]) {
  for (int c = 0; c < 8; ++c) {
    f32x4 xqa[2], xqb[2];
    #pragma unroll
    for (int mi = 0; mi < 2; ++mi) {
      xqa[mi] = *(const f32x4*)(xrow[mi] + c * 8);
      xqb[mi] = *(const f32x4*)(xrow[mi] + c * 8 + 4);
    }
    #pragma unroll
    for (int dd = 0; dd < 8; ++dd) {
      const int dl = c * 8 + dd;
      short8_t bfr0[4], bfr1[4];
      #pragma unroll
      for (int ni = 0; ni < 4; ++ni)
        bfr0[ni] = *(const short8_t*)(bbase[ni] + (size_t)dl * 16384);
      if (KF1) {
        #pragma unroll
        for (int ni = 0; ni < 4; ++ni)
          bfr1[ni] = *(const short8_t*)(bbase[ni] + (size_t)dl * 16384 + 8192);
      }
      const float* tp = thrS_lg + dl * 64;
      f32x4 ta = *(const f32x4*)(tp);
      f32x4 tb = *(const f32x4*)(tp + 4);
      short8_t afr0[2], afr1[2];
      #pragma unroll
      for (int mi = 0; mi < 2; ++mi) {
        const float xv = (dd < 4) ? xqa[mi][dd & 3] : xqb[mi][dd & 3];
        short8_t A0;
        A0[0] = (short)bfbits(lg0 ? xv : fmaxf(xv - ta[0], 0.f));
        A0[1] = (short)bfbits(fmaxf(xv - ta[1], 0.f));
        A0[2] = (short)bfbits(fmaxf(xv - ta[2], 0.f));
        A0[3] = (short)bfbits(fmaxf(xv - ta[3], 0.f));
        A0[4] = (short)bfbits(fmaxf(xv - tb[0], 0.f));
        A0[5] = (short)bfbits(fmaxf(xv - tb[1], 0.f));
        A0[6] = (short)bfbits(fmaxf(xv - tb[2], 0.f));
        A0[7] = (short)bfbits(fmaxf(xv - tb[3], 0.f));
        afr0[mi] = A0;
      }
      if (KF1) {
        f32x4 tc = *(const f32x4*)(tp + 32);
        f32x4 td = *(const f32x4*)(tp + 36);
        #pragma unroll
        for (int mi = 0; mi < 2; ++mi) {
          const float xv = (dd < 4) ? xqa[mi][dd & 3] : xqb[mi][dd & 3];
          short8_t A1;
          A1[0] = (short)bfbits(fmaxf(xv - tc[0], 0.f));
          A1[1] = (short)bfbits(fmaxf(xv - tc[1], 0.f));
          A1[2] = (short)bfbits(fmaxf(xv - tc[2], 0.f));
          A1[3] = (short)bfbits(fmaxf(xv - tc[3], 0.f));
          A1[4] = (short)bfbits(fmaxf(xv - td[0], 0.f));
          A1[5] = (short)bfbits(fmaxf(xv - td[1], 0.f));
          A1[6] = (short)bfbits(fmaxf(xv - td[2], 0.f));
          A1[7] = (short)bfbits(fmaxf(xv - td[3], 0.f));
          afr1[mi] = A1;
        }
      }
      #pragma unroll
      for (int mi = 0; mi < 2; ++mi)
        #pragma unroll
        for (int ni = 0; ni < 4; ++ni)
          acc[mi][ni] = __builtin_amdgcn_mfma_f32_16x16x32_bf16(afr0[mi], bfr0[ni], acc[mi][ni], 0, 0, 0);
      if (KF1) {
        #pragma unroll
        for (int mi = 0; mi < 2; ++mi)
          #pragma unroll
          for (int ni = 0; ni < 4; ++ni)
            acc[mi][ni] = __builtin_amdgcn_mfma_f32_16x16x32_bf16(afr1[mi], bfr1[ni], acc[mi][ni], 0, 0, 0);
      }
    }
  }
}

__global__ __launch_bounds__(256, 3) void k_proj(
    const unsigned short* __restrict__ w2f, const float* __restrict__ bp,
    const float* __restrict__ x, const int* __restrict__ fcutc,
    float* __restrict__ pbuf) {
  const int t = threadIdx.x;
  const int l = t & 63, w = t >> 6;
  const int lr = l & 15, lg = l >> 4;
  const int bM = blockIdx.x * 128;
  const int bN = blockIdx.y * 64;
  const int d0 = blockIdx.z * 64;
  __shared__ float thrS[64 * 64];     // 16 KB
  __shared__ float slab[128 * 68];    // 34.8 KB: staged 128x64 C tile

  for (int i = t; i < 4096; i += 256) {
    const int dl = i >> 6, f = i & 63;
    thrS[i] = (f >= 1) ? bp[(size_t)(d0 + dl) * NKBP + f - 1] : 0.0f;
  }
  __syncthreads();

  f32x4 acc[2][4];
  #pragma unroll
  for (int mi = 0; mi < 2; ++mi)
    #pragma unroll
    for (int ni = 0; ni < 4; ++ni) acc[mi][ni] = (f32x4){0.f, 0.f, 0.f, 0.f};

  const bool lg0 = (lg == 0);
  const unsigned short* bbase[4];
  #pragma unroll
  for (int ni = 0; ni < 4; ++ni)
    bbase[ni] = w2f + (size_t)d0 * 16384 + (size_t)(bN + ni * 16 + lr) * 8 + (size_t)lg * 2048;
  const float* xrow[2];
  #pragma unroll
  for (int mi = 0; mi < 2; ++mi)
    xrow[mi] = x + (size_t)(bM + w * 32 + mi * 16 + lr) * ND + d0;

  const int nkf = fcutc[blockIdx.z];
  if (nkf == 1) proj_kloop<false>(bbase, xrow, thrS + lg * 8, lg0, acc);
  else          proj_kloop<true >(bbase, xrow, thrS + lg * 8, lg0, acc);

  // stage into wave-local slab rows (no barrier: each wave stages and stores its own 32 rows)
  #pragma unroll
  for (int mi = 0; mi < 2; ++mi)
    #pragma unroll
    for (int ni = 0; ni < 4; ++ni)
      #pragma unroll
      for (int r = 0; r < 4; ++r)
        slab[(w * 32 + mi * 16 + lg * 4 + r) * 68 + ni * 16 + lr] = acc[mi][ni][r];

  // store tile-major: pbuf[z][tile][row(128)][col(64)], tile = bx*4+by
  // each instruction: 16 lanes/row x f32x4, 4 rows => 1KB contiguous
  float* ppt = pbuf + (size_t)blockIdx.z * 2097152 + (size_t)(blockIdx.x * 4 + blockIdx.y) * 8192;
  const int c4 = (l & 15) * 4;
  #pragma unroll
  for (int p = 0; p < 8; ++p) {
    const int row = w * 32 + p * 4 + (l >> 4);
    f32x4 v = *(const f32x4*)(slab + row * 68 + c4);
    *(f32x4*)(ppt + row * 64 + c4) = v;
  }
}

// ---------------- K4: combine partials, iterated in tile-major order (linear pbuf reads) ----------------
__global__ void k_comb(const float* __restrict__ x, const float* __restrict__ pbuf,
                       const float* __restrict__ cbuf, const float* __restrict__ pb,
                       float* __restrict__ xe) {
  const size_t j = ((size_t)blockIdx.x * 256 + threadIdx.x) * 4;  // tile-major linear index
  const int tile = (int)(j >> 13);          // 8192 floats per tile
  const int q    = (int)(j & 8191);
  const int r    = q >> 6;                  // row within tile (0..127)
  const int c    = q & 63;                  // col within tile (0..63)
  const int row  = (tile >> 2) * 128 + r;   // bx*128 + r
  const int col  = (tile & 3) * 64 + c;     // by*64 + c
  f32x4 s = *(const f32x4*)(pbuf + j);
  #pragma unroll
  for (int p = 1; p < NSPLIT; ++p)
    s += *(const f32x4*)(pbuf + (size_t)p * 2097152 + j);
  f32x4 cv = *(const f32x4*)(cbuf + col);
  f32x4 pv = *(const f32x4*)(pb + col);
  const size_t oidx = (size_t)row * ND + col;
  f32x4 xv = *(const f32x4*)(x + oidx);
  *(f32x4*)(xe + oidx) = xv + 0.1f * (s + cv + pv);
}

// ---------------- K5 (fast): 32 rows x 4 d per block; per-wave d; 1KB-burst stores ----------------
__global__ __launch_bounds__(256, 3) void k_emb3(
    const float* __restrict__ x, const unsigned short* __restrict__ bwT,
    const float* __restrict__ bb, const float* __restrict__ thrT,
    const int* __restrict__ fdv, float* __restrict__ oe) {
  const int dc = blockIdx.x;          // d-chunk of 4
  const int b0 = blockIdx.y * 32;
  const int t = threadIdx.x;
  const int l = t & 63, w = t >> 6;   // wave w owns d = dc*4 + w
  const int lr = l & 15, lg = l >> 4;
  const int d = dc * 4 + w;
  __shared__ float slab[32 * 260];    // 33.3 KB

  const int nkf = (fdv[d] > 32) ? 2 : 1;

  float xg[2];
  xg[0] = x[(size_t)(b0 + lr) * ND + d];
  xg[1] = x[(size_t)(b0 + 16 + lr) * ND + d];

  f32x4 ta = *(const f32x4*)(thrT + d * 64 + lg * 8);
  f32x4 tb = *(const f32x4*)(thrT + d * 64 + lg * 8 + 4);
  const bool lg0 = (lg == 0);

  float bbv[4];
  #pragma unroll
  for (int ni = 0; ni < 4; ++ni) bbv[ni] = bb[(size_t)d * 64 + ni * 16 + lr];

  const unsigned short* bk0 = bwT + ((size_t)d * 8 + lg) * 512;
  short8_t bfr0[4];
  #pragma unroll
  for (int ni = 0; ni < 4; ++ni)
    bfr0[ni] = *(const short8_t*)(bk0 + (ni * 16 + lr) * 8);

  short8_t afr0[2];
  #pragma unroll
  for (int mi = 0; mi < 2; ++mi) {
    const float xv = xg[mi];
    short8_t A0;
    A0[0] = (short)bfbits(lg0 ? xv : fmaxf(xv - ta[0], 0.f));
    A0[1] = (short)bfbits(fmaxf(xv - ta[1], 0.f));
    A0[2] = (short)bfbits(fmaxf(xv - ta[2], 0.f));
    A0[3] = (short)bfbits(fmaxf(xv - ta[3], 0.f));
    A0[4] = (short)bfbits(fmaxf(xv - tb[0], 0.f));
    A0[5] = (short)bfbits(fmaxf(xv - tb[1], 0.f));
    A0[6] = (short)bfbits(fmaxf(xv - tb[2], 0.f));
    A0[7] = (short)bfbits(fmaxf(xv - tb[3], 0.f));
    afr0[mi] = A0;
  }

  f32x4 acc[2][4];
  #pragma unroll
  for (int mi = 0; mi < 2; ++mi)
    #pragma unroll
    for (int ni = 0; ni < 4; ++ni) acc[mi][ni] = (f32x4){0.f, 0.f, 0.f, 0.f};
  #pragma unroll
  for (int mi = 0; mi < 2; ++mi)
    #pragma unroll
    for (int ni = 0; ni < 4; ++ni)
      acc[mi][ni] = __builtin_amdgcn_mfma_f32_16x16x32_bf16(afr0[mi], bfr0[ni], acc[mi][ni], 0, 0, 0);

  if (nkf == 2) {
    f32x4 tc = *(const f32x4*)(thrT + d * 64 + 32 + lg * 8);
    f32x4 td = *(const f32x4*)(thrT + d * 64 + 36 + lg * 8);
    const unsigned short* bk1 = bwT + ((size_t)d * 8 + 4 + lg) * 512;
    short8_t afr1[2], bfr1[4];
    #pragma unroll
    for (int ni = 0; ni < 4; ++ni)
      bfr1[ni] = *(const short8_t*)(bk1 + (ni * 16 + lr) * 8);
    #pragma unroll
    for (int mi = 0; mi < 2; ++mi) {
      const float xv = xg[mi];
      short8_t A1;
      A1[0] = (short)bfbits(fmaxf(xv - tc[0], 0.f));
      A1[1] = (short)bfbits(fmaxf(xv - tc[1], 0.f));
      A1[2] = (short)bfbits(fmaxf(xv - tc[2], 0.f));
      A1[3] = (short)bfbits(fmaxf(xv - tc[3], 0.f));
      A1[4] = (short)bfbits(fmaxf(xv - td[0], 0.f));
      A1[5] = (short)bfbits(fmaxf(xv - td[1], 0.f));
      A1[6] = (short)bfbits(fmaxf(xv - td[2], 0.f));
      A1[7] = (short)bfbits(fmaxf(xv - td[3], 0.f));
      afr1[mi] = A1;
    }
    #pragma unroll
    for (int mi = 0; mi < 2; ++mi)
      #pragma unroll
      for (int ni = 0; ni < 4; ++ni)
        acc[mi][ni] = __builtin_amdgcn_mfma_f32_16x16x32_bf16(afr1[mi], bfr1[ni], acc[mi][ni], 0, 0, 0);
  }

  #pragma unroll
  for (int ni = 0; ni < 4; ++ni)
    #pragma unroll
    for (int mi = 0; mi < 2; ++mi)
      #pragma unroll
      for (int r = 0; r < 4; ++r)
        slab[(mi * 16 + lg * 4 + r) * 260 + w * 64 + ni * 16 + lr] = acc[mi][ni][r] + bbv[ni];
  __syncthreads();

  #pragma unroll
  for (int p = 0; p < 8; ++p) {
    const int row = w * 8 + p;
    f32x4 v = *(const f32x4*)(slab + row * 260 + l * 4);
    *(f32x4*)(oe + (size_t)(b0 + row) * NDE + dc * 256 + l * 4) = v;
  }
}

// ---------------- K5 (fallback): round-8 structure, d-fastest grid ----------------
__global__ __launch_bounds__(256, 2) void k_emb_fb(
    const float* __restrict__ x, const float* __restrict__ bw,
    const float* __restrict__ bb, const float* __restrict__ bp,
    const int* __restrict__ fdv, float* __restrict__ oe) {
  const int d = blockIdx.x;
  const int b0 = blockIdx.y * 256;
  const int t = threadIdx.x;
  const int l = t & 63, w = t >> 6;
  const int lr = l & 15, lg = l >> 4;
  __shared__ unsigned short btS[64 * 72];
  __shared__ float thrF[64];
  __shared__ float bbS[64];
  __shared__ float cS[4 * 64 * 68];

  const int nkf = (fdv[d] > 32) ? 2 : 1;
  float xg[4];
  #pragma unroll
  for (int mi = 0; mi < 4; ++mi)
    xg[mi] = x[(size_t)(b0 + w * 64 + mi * 16 + lr) * ND + d];

  if (t < 64) thrF[t] = (t >= 1) ? bp[(size_t)d * NKBP + t - 1] : 0.0f;
  else if (t < 128) bbS[t - 64] = bb[(size_t)d * 64 + (t - 64)];
  {
    const float* bwd = bw + (size_t)d * 4096;
    const int f = t >> 2, e0 = (t & 3) * 16;
    #pragma unroll
    for (int q = 0; q < 4; ++q) {
      f32x4 v = *(const f32x4*)(bwd + f * 64 + e0 + q * 4);
      #pragma unroll
      for (int r = 0; r < 4; ++r) {
        const int e = e0 + q * 4 + r;
        btS[e * 72 + f] = bfbits(v[r]);
      }
    }
  }
  __syncthreads();

  f32x4 ta = *(const f32x4*)(thrF + lg * 8);
  f32x4 tb = *(const f32x4*)(thrF + lg * 8 + 4);
  const bool lg0 = (lg == 0);

  short8_t afr0[4];
  #pragma unroll
  for (int mi = 0; mi < 4; ++mi) {
    const float xv = xg[mi];
    short8_t A0;
    A0[0] = (short)bfbits(lg0 ? xv : fmaxf(xv - ta[0], 0.f));
    A0[1] = (short)bfbits(fmaxf(xv - ta[1], 0.f));
    A0[2] = (short)bfbits(fmaxf(xv - ta[2], 0.f));
    A0[3] = (short)bfbits(fmaxf(xv - ta[3], 0.f));
    A0[4] = (short)bfbits(fmaxf(xv - tb[0], 0.f));
    A0[5] = (short)bfbits(fmaxf(xv - tb[1], 0.f));
    A0[6] = (short)bfbits(fmaxf(xv - tb[2], 0.f));
    A0[7] = (short)bfbits(fmaxf(xv - tb[3], 0.f));
    afr0[mi] = A0;
  }
  short8_t bfr0[4];
  #pragma unroll
  for (int ni = 0; ni < 4; ++ni) {
    const int e = ni * 16 + lr;
    bfr0[ni] = *(const short8_t*)(btS + e * 72 + lg * 8);
  }
  f32x4 acc[4][4];
  #pragma unroll
  for (int mi = 0; mi < 4; ++mi)
    #pragma unroll
    for (int ni = 0; ni < 4; ++ni) acc[mi][ni] = (f32x4){0.f, 0.f, 0.f, 0.f};
  #pragma unroll
  for (int mi = 0; mi < 4; ++mi)
    #pragma unroll
    for (int ni = 0; ni < 4; ++ni)
      acc[mi][ni] = __builtin_amdgcn_mfma_f32_16x16x32_bf16(afr0[mi], bfr0[ni], acc[mi][ni], 0, 0, 0);

  if (nkf == 2) {
    f32x4 tc = *(const f32x4*)(thrF + 32 + lg * 8);
    f32x4 td = *(const f32x4*)(thrF + 36 + lg * 8);
    short8_t afr1[4], bfr1[4];
    #pragma unroll
    for (int mi = 0; mi < 4; ++mi) {
      const float xv = xg[mi];
      short8_t A1;
      A1[0] = (short)bfbits(fmaxf(xv - tc[0], 0.f));
      A1[1] = (short)bfbits(fmaxf(xv - tc[1], 0.f));
      A1[2] = (short)bfbits(fmaxf(xv - tc[2], 0.f));
      A1[3] = (short)bfbits(fmaxf(xv - tc[3], 0.f));
      A1[4] = (short)bfbits(fmaxf(xv - td[0], 0.f));
      A1[5] = (short)bfbits(fmaxf(xv - td[1], 0.f));
      A1[6] = (short)bfbits(fmaxf(xv - td[2], 0.f));
      A1[7] = (short)bfbits(fmaxf(xv - td[3], 0.f));
      afr1[mi] = A1;
    }
    #pragma unroll
    for (int ni = 0; ni < 4; ++ni) {
      const int e = ni * 16 + lr;
      bfr1[ni] = *(const short8_t*)(btS + e * 72 + 32 + lg * 8);
    }
    #pragma unroll
    for (int mi = 0; mi < 4; ++mi)
      #pragma unroll
      for (int ni = 0; ni < 4; ++ni)
        acc[mi][ni] = __builtin_amdgcn_mfma_f32_16x16x32_bf16(afr1[mi], bfr1[ni], acc[mi][ni], 0, 0, 0);
  }

  #pragma unroll
  for (int ni = 0; ni < 4; ++ni) {
    const float bbv = bbS[ni * 16 + lr];
    #pragma unroll
    for (int mi = 0; mi < 4; ++mi) {
      const int rw = mi * 16 + lg * 4;
      #pragma unroll
      for (int r = 0; r < 4; ++r)
        cS[w * 4352 + (rw + r) * 68 + ni * 16 + lr] = acc[mi][ni][r] + bbv;
    }
  }
  __syncthreads();

  const int rsub = t >> 4;
  const int c4 = (t & 15) * 4;
  #pragma unroll
  for (int p = 0; p < 16; ++p) {
    const int row = p * 16 + rsub;
    const int wsrc = row >> 6, wr = row & 63;
    f32x4 v = *(const f32x4*)(cS + wsrc * 4352 + wr * 68 + c4);
    *(f32x4*)(oe + (size_t)(b0 + row) * NDE + d * 64 + c4) = v;
  }
}

extern "C" void kernel_launch(void* const* d_in, const int* in_sizes, int n_in,
                              void* d_out, int out_size, void* d_ws, size_t ws_size,
                              hipStream_t stream) {
  const float* x    = (const float*)d_in[0];
  const float* bw   = (const float*)d_in[1];
  const float* bb   = (const float*)d_in[2];
  const float* pw   = (const float*)d_in[3];
  const float* pb   = (const float*)d_in[4];
  const float* bmin = (const float*)d_in[5];
  const float* draw = (const float*)d_in[6];

  float* out    = (float*)d_out;
  float* out_x  = out;                          // [8192*256]
  float* out_e  = out + (size_t)NB * ND;        // [8192*256*64]
  float* out_bp = out_e + (size_t)NB * NDE;     // [256*63]

  unsigned short* w2f = (unsigned short*)out_x; // 8.39 MB, overwritten by k_comb
  float* cbuf    = out_e;                            // 256 f32
  float* pbuf    = out_e + 65536;                    // NSPLIT * 2097152 f32 = 33.5 MB
  float* cb_part = out_e + 65536 + NSPLIT * 2097152; // 256 KB

  // d_ws layout: bmax[256] fdv[256] fcutc[8] | thrT[16384] | bwT[1M ushort]
  float* wsf  = (float*)d_ws;
  float* bmax = wsf;
  int*   fdv  = (int*)wsf + 256;
  int*   fcutc= (int*)wsf + 512;
  float* thrT = wsf + 768;
  unsigned short* bwT = (unsigned short*)(wsf + 768 + 16384);
  const bool FAST = ws_size >= (size_t)(768 + 16384) * 4 + (size_t)2097152 * 2 + 256;

  if (FAST)
    k_mp <<<dim3(256),         dim3(256), 0, stream>>>(x, bw, bmax, bwT);
  else
    k_maxx<<<dim3(256),        dim3(256), 0, stream>>>(x, bmax);
  k_bp  <<<dim3(1),            dim3(256), 0, stream>>>(bmin, draw, bmax, out_bp, fdv, fcutc,
                                                       FAST ? thrT : (float*)nullptr);
  k_w2  <<<dim3(256),          dim3(256), 0, stream>>>(bw, pw, bb, fcutc, w2f, cb_part);
  k_cbr <<<dim3(1),            dim3(256), 0, stream>>>(cb_part, cbuf);
  k_proj<<<dim3(64, 4, NSPLIT),dim3(256), 0, stream>>>(w2f, out_bp, x, fcutc, pbuf);
  k_comb<<<dim3(2048),         dim3(256), 0, stream>>>(x, pbuf, cbuf, pb, out_x);
  if (FAST)
    k_emb3<<<dim3(64, 256),    dim3(256), 0, stream>>>(x, bwT, bb, thrT, fdv, out_e);
  else
    k_emb_fb<<<dim3(256, 32),  dim3(256), 0, stream>>>(x, bw, bb, out_bp, fdv, out_e);
}

// Round 16
// 239.808 us; speedup vs baseline: 1.0210x; 1.0210x over previous
//
#include <hip/hip_runtime.h>
#include <hip/hip_bf16.h>

#define NB 8192
#define ND 256
#define NKBP 63
#define NF 64
#define NE 64
#define NKP 16384   // D*F
#define NDE 16384   // D*E
#define NSPLIT 4    // split-K factor for k_proj (64 d per block)

typedef __attribute__((ext_vector_type(8))) short short8_t;
typedef __attribute__((ext_vector_type(4))) short short4_t;
typedef __attribute__((ext_vector_type(4))) float f32x4;

__device__ __forceinline__ unsigned short bfbits(float v) {
  union { __hip_bfloat16 b; unsigned short u; } cv;
  cv.b = __float2bfloat16(v);
  return cv.u;
}
__device__ __forceinline__ float bf2f(unsigned short s) {
  return __uint_as_float(((unsigned)s) << 16);
}

// ---------------- K0 (fused): per-block max of x + bwT fragment-native prep ----------------
__global__ void k_mp(const float* __restrict__ x, const float* __restrict__ bw,
                     float* __restrict__ bmax, unsigned short* __restrict__ bwT) {
  const int t = threadIdx.x;
  const float* px = x + (size_t)blockIdx.x * 8192;
  float m = 0.f;  // clamped at 0: conservative (only ever raises Fd)
  #pragma unroll 4
  for (int i = t; i < 8192; i += 256) m = fmaxf(m, px[i]);
  #pragma unroll
  for (int off = 32; off > 0; off >>= 1) m = fmaxf(m, __shfl_down(m, off, 64));
  __shared__ float red[4];
  if ((t & 63) == 0) red[t >> 6] = m;
  __syncthreads();
  if (t == 0) bmax[blockIdx.x] = fmaxf(fmaxf(red[0], red[1]), fmaxf(red[2], red[3]));
  // bwT prep for d = blockIdx.x: elem (d,e,f) at bwT[(((d*2+kf)*4+lg)*64+e)*8+j]
  const int d = blockIdx.x;
  const int f = t >> 2, e0 = (t & 3) * 16;
  const int kf = f >> 5, lg = (f >> 3) & 3, j = f & 7;
  const size_t base = ((((size_t)d * 2 + kf) * 4 + lg) * 64) * 8 + j;
  #pragma unroll
  for (int q = 0; q < 4; ++q) {
    f32x4 v = *(const f32x4*)(bw + (size_t)d * 4096 + f * 64 + e0 + q * 4);
    #pragma unroll
    for (int r = 0; r < 4; ++r)
      bwT[base + (size_t)(e0 + q * 4 + r) * 8] = bfbits(v[r]);
  }
}

// ---------------- K0b (fallback when !FAST): plain maxx ----------------
__global__ void k_maxx(const float* __restrict__ x, float* __restrict__ bmax) {
  const int t = threadIdx.x;
  const float* px = x + (size_t)blockIdx.x * 8192;
  float m = 0.f;
  #pragma unroll 4
  for (int i = t; i < 8192; i += 256) m = fmaxf(m, px[i]);
  #pragma unroll
  for (int off = 32; off > 0; off >>= 1) m = fmaxf(m, __shfl_down(m, off, 64));
  __shared__ float red[4];
  if ((t & 63) == 0) red[t >> 6] = m;
  __syncthreads();
  if (t == 0) bmax[blockIdx.x] = fmaxf(fmaxf(red[0], red[1]), fmaxf(red[2], red[3]));
}

// ---------------- K1: breakpoints + effective-K flags + threshold table ----------------
__global__ void k_bp(const float* __restrict__ bmin, const float* __restrict__ draw,
                     const float* __restrict__ bmax, float* __restrict__ obp,
                     int* __restrict__ fdv, int* __restrict__ fcutc,
                     float* __restrict__ thrT) {
  const int d = threadIdx.x;  // 256 threads, one per d
  __shared__ float drawS[ND * NKBP];   // 63 KB, coalesced stage
  __shared__ float mred[256];
  __shared__ int fds[256];
  mred[d] = bmax[d];
  for (int i = d; i < ND * NKBP; i += 256) drawS[i] = draw[i];
  __syncthreads();
  for (int s = 128; s > 0; s >>= 1) {
    if (d < s) mred[d] = fmaxf(mred[d], mred[d + s]);
    __syncthreads();
  }
  const float maxx = mred[0];
  float a = bmin[d];
  int cnt = 0;
  if (thrT) thrT[d * 64] = 0.0f;
  for (int j = 0; j < NKBP; ++j) {
    float r = drawS[d * NKBP + j];
    a += fmaxf(r, 0.f) + log1pf(expf(-fabsf(r)));
    obp[d * NKBP + j] = a;
    if (thrT) thrT[d * 64 + 1 + j] = a;
    cnt += (a < maxx) ? 1 : 0;
  }
  const int Fd = 1 + cnt;
  fdv[d] = Fd;
  fds[d] = Fd;
  __syncthreads();
  if (d < NSPLIT) {
    int mx = 0;
    for (int k = 0; k < 64; ++k) mx = max(mx, fds[d * 64 + k]);
    fcutc[d] = (mx > 32) ? 2 : 1;
  }
}

// ---------------- K2: W2 (fragment-native blocked layout) + cbias partials ----------------
__global__ __launch_bounds__(256, 2) void k_w2(
    const float* __restrict__ bw, const float* __restrict__ pw,
    const float* __restrict__ bb, const int* __restrict__ fcutc,
    unsigned short* __restrict__ w2f, float* __restrict__ cb_part) {
  const int d = blockIdx.x;
  const int t = threadIdx.x;
  const int l = t & 63, w = t >> 6;
  const int lr = l & 15, lg = l >> 4;
  const int nkf = fcutc[d >> 6];   // 1 or 2
  __shared__ unsigned short pwS[256 * 72];
  __shared__ unsigned short bwS[64 * 72];
  __shared__ float bbS[64];

  {
    const int rr = t >> 4, e0 = (t & 15) * 4;
    #pragma unroll
    for (int it = 0; it < 16; ++it) {
      const int n = it * 16 + rr;
      f32x4 v = *(const f32x4*)(pw + (size_t)n * NDE + d * 64 + e0);
      short4_t s;
      s[0] = (short)bfbits(v[0]); s[1] = (short)bfbits(v[1]);
      s[2] = (short)bfbits(v[2]); s[3] = (short)bfbits(v[3]);
      *(short4_t*)(pwS + n * 72 + e0) = s;
    }
    const int itmax = (nkf == 2) ? 4 : 2;
    for (int it = 0; it < itmax; ++it) {
      const int f = it * 16 + rr;
      f32x4 v = *(const f32x4*)(bw + (size_t)d * 4096 + f * 64 + e0);
      short4_t s;
      s[0] = (short)bfbits(v[0]); s[1] = (short)bfbits(v[1]);
      s[2] = (short)bfbits(v[2]); s[3] = (short)bfbits(v[3]);
      *(short4_t*)(bwS + f * 72 + e0) = s;
    }
    if (t < 64) bbS[t] = bb[(size_t)d * 64 + t];
  }
  __syncthreads();

  f32x4 acc[4][4];
  #pragma unroll
  for (int mi = 0; mi < 4; ++mi)
    #pragma unroll
    for (int ni = 0; ni < 4; ++ni) acc[mi][ni] = (f32x4){0.f, 0.f, 0.f, 0.f};

  const int nimax = (nkf == 2) ? 4 : 2;
  for (int kf = 0; kf < nkf; ++kf) {
    short8_t afr[4], bfr[4];
    #pragma unroll
    for (int mi = 0; mi < 4; ++mi) {
      const int n = w * 64 + mi * 16 + lr;
      afr[mi] = *(const short8_t*)(pwS + n * 72 + kf * 32 + lg * 8);
    }
    for (int ni = 0; ni < nimax; ++ni) {
      const int f = ni * 16 + lr;
      bfr[ni] = *(const short8_t*)(bwS + f * 72 + kf * 32 + lg * 8);
    }
    for (int ni = 0; ni < nimax; ++ni)
      #pragma unroll
      for (int mi = 0; mi < 4; ++mi)
        acc[mi][ni] = __builtin_amdgcn_mfma_f32_16x16x32_bf16(afr[mi], bfr[ni], acc[mi][ni], 0, 0, 0);
  }

  #pragma unroll
  for (int mi = 0; mi < 4; ++mi)
    for (int ni = 0; ni < nimax; ++ni) {
      const int kf_s = ni >> 1;
      const int lgp  = (ni * 2 + (lr >> 3)) & 3;
      const int jj   = lr & 7;
      const int nb   = w * 64 + mi * 16 + lg * 4;
      const size_t base = (((size_t)d * 2 + kf_s) * 4 + lgp) * 256;
      #pragma unroll
      for (int r = 0; r < 4; ++r)
        w2f[(base + (nb + r)) * 8 + jj] = bfbits(acc[mi][ni][r]);
    }

  {
    float cacc = 0.f;
    #pragma unroll 8
    for (int e = 0; e < 64; ++e) cacc += bf2f(pwS[t * 72 + e]) * bbS[e];
    cb_part[(size_t)d * 256 + t] = cacc;
  }
}

// ---------------- K2r: cbias[n] = sum_d cb_part[d][n] ----------------
__global__ void k_cbr(const float* __restrict__ cb_part, float* __restrict__ c) {
  const int t = threadIdx.x;
  float a0 = 0.f, a1 = 0.f, a2 = 0.f, a3 = 0.f;
  for (int d = 0; d < ND; d += 4) {
    a0 += cb_part[(size_t)(d + 0) * 256 + t];
    a1 += cb_part[(size_t)(d + 1) * 256 + t];
    a2 += cb_part[(size_t)(d + 2) * 256 + t];
    a3 += cb_part[(size_t)(d + 3) * 256 + t];
  }
  c[t] = (a0 + a1) + (a2 + a3);
}

// ---------------- K3: projection GEMM partials (r13 structure, occupancy 4) ----------------
template<bool KF1>
__device__ __forceinline__ void proj_kloop(
    const unsigned short* const (&bbase)[4], const float* const (&xrow)[2],
    const float* thrS_lg, bool lg0, f32x4 (&acc)[2][4]) {
  for (int c = 0; c < 8; ++c) {
    f32x4 xqa[2], xqb[2];
    #pragma unroll
    for (int mi = 0; mi < 2; ++mi) {
      xqa[mi] = *(const f32x4*)(xrow[mi] + c * 8);
      xqb[mi] = *(const f32x4*)(xrow[mi] + c * 8 + 4);
    }
    #pragma unroll
    for (int dd = 0; dd < 8; ++dd) {
      const int dl = c * 8 + dd;
      short8_t bfr0[4], bfr1[4];
      #pragma unroll
      for (int ni = 0; ni < 4; ++ni)
        bfr0[ni] = *(const short8_t*)(bbase[ni] + (size_t)dl * 16384);
      if (KF1) {
        #pragma unroll
        for (int ni = 0; ni < 4; ++ni)
          bfr1[ni] = *(const short8_t*)(bbase[ni] + (size_t)dl * 16384 + 8192);
      }
      const float* tp = thrS_lg + dl * 64;
      f32x4 ta = *(const f32x4*)(tp);
      f32x4 tb = *(const f32x4*)(tp + 4);
      short8_t afr0[2], afr1[2];
      #pragma unroll
      for (int mi = 0; mi < 2; ++mi) {
        const float xv = (dd < 4) ? xqa[mi][dd & 3] : xqb[mi][dd & 3];
        short8_t A0;
        A0[0] = (short)bfbits(lg0 ? xv : fmaxf(xv - ta[0], 0.f));
        A0[1] = (short)bfbits(fmaxf(xv - ta[1], 0.f));
        A0[2] = (short)bfbits(fmaxf(xv - ta[2], 0.f));
        A0[3] = (short)bfbits(fmaxf(xv - ta[3], 0.f));
        A0[4] = (short)bfbits(fmaxf(xv - tb[0], 0.f));
        A0[5] = (short)bfbits(fmaxf(xv - tb[1], 0.f));
        A0[6] = (short)bfbits(fmaxf(xv - tb[2], 0.f));
        A0[7] = (short)bfbits(fmaxf(xv - tb[3], 0.f));
        afr0[mi] = A0;
      }
      if (KF1) {
        f32x4 tc = *(const f32x4*)(tp + 32);
        f32x4 td = *(const f32x4*)(tp + 36);
        #pragma unroll
        for (int mi = 0; mi < 2; ++mi) {
          const float xv = (dd < 4) ? xqa[mi][dd & 3] : xqb[mi][dd & 3];
          short8_t A1;
          A1[0] = (short)bfbits(fmaxf(xv - tc[0], 0.f));
          A1[1] = (short)bfbits(fmaxf(xv - tc[1], 0.f));
          A1[2] = (short)bfbits(fmaxf(xv - tc[2], 0.f));
          A1[3] = (short)bfbits(fmaxf(xv - tc[3], 0.f));
          A1[4] = (short)bfbits(fmaxf(xv - td[0], 0.f));
          A1[5] = (short)bfbits(fmaxf(xv - td[1], 0.f));
          A1[6] = (short)bfbits(fmaxf(xv - td[2], 0.f));
          A1[7] = (short)bfbits(fmaxf(xv - td[3], 0.f));
          afr1[mi] = A1;
        }
      }
      #pragma unroll
      for (int mi = 0; mi < 2; ++mi)
        #pragma unroll
        for (int ni = 0; ni < 4; ++ni)
          acc[mi][ni] = __builtin_amdgcn_mfma_f32_16x16x32_bf16(afr0[mi], bfr0[ni], acc[mi][ni], 0, 0, 0);
      if (KF1) {
        #pragma unroll
        for (int mi = 0; mi < 2; ++mi)
          #pragma unroll
          for (int ni = 0; ni < 4; ++ni)
            acc[mi][ni] = __builtin_amdgcn_mfma_f32_16x16x32_bf16(afr1[mi], bfr1[ni], acc[mi][ni], 0, 0, 0);
      }
    }
  }
}

__global__ __launch_bounds__(256, 4) void k_proj(
    const unsigned short* __restrict__ w2f, const float* __restrict__ bp,
    const float* __restrict__ x, const int* __restrict__ fcutc,
    float* __restrict__ pbuf) {
  const int t = threadIdx.x;
  const int l = t & 63, w = t >> 6;
  const int lr = l & 15, lg = l >> 4;
  const int bM = blockIdx.x * 128;
  const int bN = blockIdx.y * 64;
  const int d0 = blockIdx.z * 64;
  __shared__ float thrS[64 * 64];

  for (int i = t; i < 4096; i += 256) {
    const int dl = i >> 6, f = i & 63;
    thrS[i] = (f >= 1) ? bp[(size_t)(d0 + dl) * NKBP + f - 1] : 0.0f;
  }
  __syncthreads();

  f32x4 acc[2][4];
  #pragma unroll
  for (int mi = 0; mi < 2; ++mi)
    #pragma unroll
    for (int ni = 0; ni < 4; ++ni) acc[mi][ni] = (f32x4){0.f, 0.f, 0.f, 0.f};

  const bool lg0 = (lg == 0);
  const unsigned short* bbase[4];
  #pragma unroll
  for (int ni = 0; ni < 4; ++ni)
    bbase[ni] = w2f + (size_t)d0 * 16384 + (size_t)(bN + ni * 16 + lr) * 8 + (size_t)lg * 2048;
  const float* xrow[2];
  #pragma unroll
  for (int mi = 0; mi < 2; ++mi)
    xrow[mi] = x + (size_t)(bM + w * 32 + mi * 16 + lr) * ND + d0;

  const int nkf = fcutc[blockIdx.z];
  if (nkf == 1) proj_kloop<false>(bbase, xrow, thrS + lg * 8, lg0, acc);
  else          proj_kloop<true >(bbase, xrow, thrS + lg * 8, lg0, acc);

  float* pp = pbuf + (size_t)blockIdx.z * ((size_t)NB * ND);
  #pragma unroll
  for (int mi = 0; mi < 2; ++mi)
    #pragma unroll
    for (int ni = 0; ni < 4; ++ni) {
      const int col = bN + ni * 16 + lr;
      const int rowb = bM + w * 32 + mi * 16 + lg * 4;
      #pragma unroll
      for (int r = 0; r < 4; ++r)
        pp[(size_t)(rowb + r) * ND + col] = acc[mi][ni][r];
    }
}

// ---------------- K4: combine partials -> x_emb ----------------
__global__ void k_comb(const float* __restrict__ x, const float* __restrict__ pbuf,
                       const float* __restrict__ cbuf, const float* __restrict__ pb,
                       float* __restrict__ xe) {
  const size_t i = ((size_t)blockIdx.x * 256 + threadIdx.x) * 4;
  const int n = (int)(i & 255);
  f32x4 s = *(const f32x4*)(pbuf + i);
  #pragma unroll
  for (int p = 1; p < NSPLIT; ++p)
    s += *(const f32x4*)(pbuf + (size_t)p * 2097152 + i);
  f32x4 cv = *(const f32x4*)(cbuf + n);
  f32x4 pv = *(const f32x4*)(pb + n);
  f32x4 xv = *(const f32x4*)(x + i);
  *(f32x4*)(xe + i) = xv + 0.1f * (s + cv + pv);
}

// ---------------- K5 (fast): 32 rows x 4 d per block; per-wave d; 1KB-burst stores ----------------
__global__ __launch_bounds__(256, 3) void k_emb3(
    const float* __restrict__ x, const unsigned short* __restrict__ bwT,
    const float* __restrict__ bb, const float* __restrict__ thrT,
    const int* __restrict__ fdv, float* __restrict__ oe) {
  const int dc = blockIdx.x;          // d-chunk of 4
  const int b0 = blockIdx.y * 32;
  const int t = threadIdx.x;
  const int l = t & 63, w = t >> 6;   // wave w owns d = dc*4 + w
  const int lr = l & 15, lg = l >> 4;
  const int d = dc * 4 + w;
  __shared__ float slab[32 * 260];    // 33.3 KB

  const int nkf = (fdv[d] > 32) ? 2 : 1;

  float xg[2];
  xg[0] = x[(size_t)(b0 + lr) * ND + d];
  xg[1] = x[(size_t)(b0 + 16 + lr) * ND + d];

  f32x4 ta = *(const f32x4*)(thrT + d * 64 + lg * 8);
  f32x4 tb = *(const f32x4*)(thrT + d * 64 + lg * 8 + 4);
  const bool lg0 = (lg == 0);

  float bbv[4];
  #pragma unroll
  for (int ni = 0; ni < 4; ++ni) bbv[ni] = bb[(size_t)d * 64 + ni * 16 + lr];

  const unsigned short* bk0 = bwT + ((size_t)d * 8 + lg) * 512;
  short8_t bfr0[4];
  #pragma unroll
  for (int ni = 0; ni < 4; ++ni)
    bfr0[ni] = *(const short8_t*)(bk0 + (ni * 16 + lr) * 8);

  short8_t afr0[2];
  #pragma unroll
  for (int mi = 0; mi < 2; ++mi) {
    const float xv = xg[mi];
    short8_t A0;
    A0[0] = (short)bfbits(lg0 ? xv : fmaxf(xv - ta[0], 0.f));
    A0[1] = (short)bfbits(fmaxf(xv - ta[1], 0.f));
    A0[2] = (short)bfbits(fmaxf(xv - ta[2], 0.f));
    A0[3] = (short)bfbits(fmaxf(xv - ta[3], 0.f));
    A0[4] = (short)bfbits(fmaxf(xv - tb[0], 0.f));
    A0[5] = (short)bfbits(fmaxf(xv - tb[1], 0.f));
    A0[6] = (short)bfbits(fmaxf(xv - tb[2], 0.f));
    A0[7] = (short)bfbits(fmaxf(xv - tb[3], 0.f));
    afr0[mi] = A0;
  }

  f32x4 acc[2][4];
  #pragma unroll
  for (int mi = 0; mi < 2; ++mi)
    #pragma unroll
    for (int ni = 0; ni < 4; ++ni) acc[mi][ni] = (f32x4){0.f, 0.f, 0.f, 0.f};
  #pragma unroll
  for (int mi = 0; mi < 2; ++mi)
    #pragma unroll
    for (int ni = 0; ni < 4; ++ni)
      acc[mi][ni] = __builtin_amdgcn_mfma_f32_16x16x32_bf16(afr0[mi], bfr0[ni], acc[mi][ni], 0, 0, 0);

  if (nkf == 2) {
    f32x4 tc = *(const f32x4*)(thrT + d * 64 + 32 + lg * 8);
    f32x4 td = *(const f32x4*)(thrT + d * 64 + 36 + lg * 8);
    const unsigned short* bk1 = bwT + ((size_t)d * 8 + 4 + lg) * 512;
    short8_t afr1[2], bfr1[4];
    #pragma unroll
    for (int ni = 0; ni < 4; ++ni)
      bfr1[ni] = *(const short8_t*)(bk1 + (ni * 16 + lr) * 8);
    #pragma unroll
    for (int mi = 0; mi < 2; ++mi) {
      const float xv = xg[mi];
      short8_t A1;
      A1[0] = (short)bfbits(fmaxf(xv - tc[0], 0.f));
      A1[1] = (short)bfbits(fmaxf(xv - tc[1], 0.f));
      A1[2] = (short)bfbits(fmaxf(xv - tc[2], 0.f));
      A1[3] = (short)bfbits(fmaxf(xv - tc[3], 0.f));
      A1[4] = (short)bfbits(fmaxf(xv - td[0], 0.f));
      A1[5] = (short)bfbits(fmaxf(xv - td[1], 0.f));
      A1[6] = (short)bfbits(fmaxf(xv - td[2], 0.f));
      A1[7] = (short)bfbits(fmaxf(xv - td[3], 0.f));
      afr1[mi] = A1;
    }
    #pragma unroll
    for (int mi = 0; mi < 2; ++mi)
      #pragma unroll
      for (int ni = 0; ni < 4; ++ni)
        acc[mi][ni] = __builtin_amdgcn_mfma_f32_16x16x32_bf16(afr1[mi], bfr1[ni], acc[mi][ni], 0, 0, 0);
  }

  #pragma unroll
  for (int ni = 0; ni < 4; ++ni)
    #pragma unroll
    for (int mi = 0; mi < 2; ++mi)
      #pragma unroll
      for (int r = 0; r < 4; ++r)
        slab[(mi * 16 + lg * 4 + r) * 260 + w * 64 + ni * 16 + lr] = acc[mi][ni][r] + bbv[ni];
  __syncthreads();

  #pragma unroll
  for (int p = 0; p < 8; ++p) {
    const int row = w * 8 + p;
    f32x4 v = *(const f32x4*)(slab + row * 260 + l * 4);
    *(f32x4*)(oe + (size_t)(b0 + row) * NDE + dc * 256 + l * 4) = v;
  }
}

// ---------------- K5 (fallback): round-8 structure, d-fastest grid ----------------
__global__ __launch_bounds__(256, 2) void k_emb_fb(
    const float* __restrict__ x, const float* __restrict__ bw,
    const float* __restrict__ bb, const float* __restrict__ bp,
    const int* __restrict__ fdv, float* __restrict__ oe) {
  const int d = blockIdx.x;
  const int b0 = blockIdx.y * 256;
  const int t = threadIdx.x;
  const int l = t & 63, w = t >> 6;
  const int lr = l & 15, lg = l >> 4;
  __shared__ unsigned short btS[64 * 72];
  __shared__ float thrF[64];
  __shared__ float bbS[64];
  __shared__ float cS[4 * 64 * 68];

  const int nkf = (fdv[d] > 32) ? 2 : 1;
  float xg[4];
  #pragma unroll
  for (int mi = 0; mi < 4; ++mi)
    xg[mi] = x[(size_t)(b0 + w * 64 + mi * 16 + lr) * ND + d];

  if (t < 64) thrF[t] = (t >= 1) ? bp[(size_t)d * NKBP + t - 1] : 0.0f;
  else if (t < 128) bbS[t - 64] = bb[(size_t)d * 64 + (t - 64)];
  {
    const float* bwd = bw + (size_t)d * 4096;
    const int f = t >> 2, e0 = (t & 3) * 16;
    #pragma unroll
    for (int q = 0; q < 4; ++q) {
      f32x4 v = *(const f32x4*)(bwd + f * 64 + e0 + q * 4);
      #pragma unroll
      for (int r = 0; r < 4; ++r) {
        const int e = e0 + q * 4 + r;
        btS[e * 72 + f] = bfbits(v[r]);
      }
    }
  }
  __syncthreads();

  f32x4 ta = *(const f32x4*)(thrF + lg * 8);
  f32x4 tb = *(const f32x4*)(thrF + lg * 8 + 4);
  const bool lg0 = (lg == 0);

  short8_t afr0[4];
  #pragma unroll
  for (int mi = 0; mi < 4; ++mi) {
    const float xv = xg[mi];
    short8_t A0;
    A0[0] = (short)bfbits(lg0 ? xv : fmaxf(xv - ta[0], 0.f));
    A0[1] = (short)bfbits(fmaxf(xv - ta[1], 0.f));
    A0[2] = (short)bfbits(fmaxf(xv - ta[2], 0.f));
    A0[3] = (short)bfbits(fmaxf(xv - ta[3], 0.f));
    A0[4] = (short)bfbits(fmaxf(xv - tb[0], 0.f));
    A0[5] = (short)bfbits(fmaxf(xv - tb[1], 0.f));
    A0[6] = (short)bfbits(fmaxf(xv - tb[2], 0.f));
    A0[7] = (short)bfbits(fmaxf(xv - tb[3], 0.f));
    afr0[mi] = A0;
  }
  short8_t bfr0[4];
  #pragma unroll
  for (int ni = 0; ni < 4; ++ni) {
    const int e = ni * 16 + lr;
    bfr0[ni] = *(const short8_t*)(btS + e * 72 + lg * 8);
  }
  f32x4 acc[4][4];
  #pragma unroll
  for (int mi = 0; mi < 4; ++mi)
    #pragma unroll
    for (int ni = 0; ni < 4; ++ni) acc[mi][ni] = (f32x4){0.f, 0.f, 0.f, 0.f};
  #pragma unroll
  for (int mi = 0; mi < 4; ++mi)
    #pragma unroll
    for (int ni = 0; ni < 4; ++ni)
      acc[mi][ni] = __builtin_amdgcn_mfma_f32_16x16x32_bf16(afr0[mi], bfr0[ni], acc[mi][ni], 0, 0, 0);

  if (nkf == 2) {
    f32x4 tc = *(const f32x4*)(thrF + 32 + lg * 8);
    f32x4 td = *(const f32x4*)(thrF + 36 + lg * 8);
    short8_t afr1[4], bfr1[4];
    #pragma unroll
    for (int mi = 0; mi < 4; ++mi) {
      const float xv = xg[mi];
      short8_t A1;
      A1[0] = (short)bfbits(fmaxf(xv - tc[0], 0.f));
      A1[1] = (short)bfbits(fmaxf(xv - tc[1], 0.f));
      A1[2] = (short)bfbits(fmaxf(xv - tc[2], 0.f));
      A1[3] = (short)bfbits(fmaxf(xv - tc[3], 0.f));
      A1[4] = (short)bfbits(fmaxf(xv - td[0], 0.f));
      A1[5] = (short)bfbits(fmaxf(xv - td[1], 0.f));
      A1[6] = (short)bfbits(fmaxf(xv - td[2], 0.f));
      A1[7] = (short)bfbits(fmaxf(xv - td[3], 0.f));
      afr1[mi] = A1;
    }
    #pragma unroll
    for (int ni = 0; ni < 4; ++ni) {
      const int e = ni * 16 + lr;
      bfr1[ni] = *(const short8_t*)(btS + e * 72 + 32 + lg * 8);
    }
    #pragma unroll
    for (int mi = 0; mi < 4; ++mi)
      #pragma unroll
      for (int ni = 0; ni < 4; ++ni)
        acc[mi][ni] = __builtin_amdgcn_mfma_f32_16x16x32_bf16(afr1[mi], bfr1[ni], acc[mi][ni], 0, 0, 0);
  }

  #pragma unroll
  for (int ni = 0; ni < 4; ++ni) {
    const float bbv = bbS[ni * 16 + lr];
    #pragma unroll
    for (int mi = 0; mi < 4; ++mi) {
      const int rw = mi * 16 + lg * 4;
      #pragma unroll
      for (int r = 0; r < 4; ++r)
        cS[w * 4352 + (rw + r) * 68 + ni * 16 + lr] = acc[mi][ni][r] + bbv;
    }
  }
  __syncthreads();

  const int rsub = t >> 4;
  const int c4 = (t & 15) * 4;
  #pragma unroll
  for (int p = 0; p < 16; ++p) {
    const int row = p * 16 + rsub;
    const int wsrc = row >> 6, wr = row & 63;
    f32x4 v = *(const f32x4*)(cS + wsrc * 4352 + wr * 68 + c4);
    *(f32x4*)(oe + (size_t)(b0 + row) * NDE + d * 64 + c4) = v;
  }
}

extern "C" void kernel_launch(void* const* d_in, const int* in_sizes, int n_in,
                              void* d_out, int out_size, void* d_ws, size_t ws_size,
                              hipStream_t stream) {
  const float* x    = (const float*)d_in[0];
  const float* bw   = (const float*)d_in[1];
  const float* bb   = (const float*)d_in[2];
  const float* pw   = (const float*)d_in[3];
  const float* pb   = (const float*)d_in[4];
  const float* bmin = (const float*)d_in[5];
  const float* draw = (const float*)d_in[6];

  float* out    = (float*)d_out;
  float* out_x  = out;                          // [8192*256]
  float* out_e  = out + (size_t)NB * ND;        // [8192*256*64]
  float* out_bp = out_e + (size_t)NB * NDE;     // [256*63]

  unsigned short* w2f = (unsigned short*)out_x; // 8.39 MB, overwritten by k_comb
  float* cbuf    = out_e;                            // 256 f32
  float* pbuf    = out_e + 65536;                    // NSPLIT * 2097152 f32 = 33.5 MB
  float* cb_part = out_e + 65536 + NSPLIT * 2097152; // 256 KB

  // d_ws layout: bmax[256] fdv[256] fcutc[8] | thrT[16384] | bwT[1M ushort]
  float* wsf  = (float*)d_ws;
  float* bmax = wsf;
  int*   fdv  = (int*)wsf + 256;
  int*   fcutc= (int*)wsf + 512;
  float* thrT = wsf + 768;
  unsigned short* bwT = (unsigned short*)(wsf + 768 + 16384);
  const bool FAST = ws_size >= (size_t)(768 + 16384) * 4 + (size_t)2097152 * 2 + 256;

  if (FAST)
    k_mp <<<dim3(256),         dim3(256), 0, stream>>>(x, bw, bmax, bwT);
  else
    k_maxx<<<dim3(256),        dim3(256), 0, stream>>>(x, bmax);
  k_bp  <<<dim3(1),            dim3(256), 0, stream>>>(bmin, draw, bmax, out_bp, fdv, fcutc,
                                                       FAST ? thrT : (float*)nullptr);
  k_w2  <<<dim3(256),          dim3(256), 0, stream>>>(bw, pw, bb, fcutc, w2f, cb_part);
  k_cbr <<<dim3(1),            dim3(256), 0, stream>>>(cb_part, cbuf);
  k_proj<<<dim3(64, 4, NSPLIT),dim3(256), 0, stream>>>(w2f, out_bp, x, fcutc, pbuf);
  k_comb<<<dim3(2048),         dim3(256), 0, stream>>>(x, pbuf, cbuf, pb, out_x);
  if (FAST)
    k_emb3<<<dim3(64, 256),    dim3(256), 0, stream>>>(x, bwT, bb, thrT, fdv, out_e);
  else
    k_emb_fb<<<dim3(256, 32),  dim3(256), 0, stream>>>(x, bw, bb, out_bp, fdv, out_e);
}

// Round 17
// 235.212 us; speedup vs baseline: 1.0410x; 1.0195x over previous
//
#include <hip/hip_runtime.h>
#include <hip/hip_bf16.h>

#define NB 8192
#define ND 256
#define NKBP 63
#define NF 64
#define NE 64
#define NKP 16384   // D*F
#define NDE 16384   // D*E
#define NSPLIT 4    // split-K factor for k_proj (64 d per block)

typedef __attribute__((ext_vector_type(8))) short short8_t;
typedef __attribute__((ext_vector_type(4))) short short4_t;
typedef __attribute__((ext_vector_type(4))) float f32x4;

__device__ __forceinline__ unsigned short bfbits(float v) {
  union { __hip_bfloat16 b; unsigned short u; } cv;
  cv.b = __float2bfloat16(v);
  return cv.u;
}
__device__ __forceinline__ float bf2f(unsigned short s) {
  return __uint_as_float(((unsigned)s) << 16);
}

// ---------------- K0 (fused): per-block max of x + bwT fragment-native prep ----------------
__global__ void k_mp(const float* __restrict__ x, const float* __restrict__ bw,
                     float* __restrict__ bmax, unsigned short* __restrict__ bwT) {
  const int t = threadIdx.x;
  const float* px = x + (size_t)blockIdx.x * 8192;
  float m = 0.f;  // clamped at 0: conservative (only ever raises Fd)
  #pragma unroll 4
  for (int i = t; i < 8192; i += 256) m = fmaxf(m, px[i]);
  #pragma unroll
  for (int off = 32; off > 0; off >>= 1) m = fmaxf(m, __shfl_down(m, off, 64));
  __shared__ float red[4];
  if ((t & 63) == 0) red[t >> 6] = m;
  __syncthreads();
  if (t == 0) bmax[blockIdx.x] = fmaxf(fmaxf(red[0], red[1]), fmaxf(red[2], red[3]));
  // bwT prep for d = blockIdx.x: elem (d,e,f) at bwT[(((d*2+kf)*4+lg)*64+e)*8+j]
  const int d = blockIdx.x;
  const int f = t >> 2, e0 = (t & 3) * 16;
  const int kf = f >> 5, lg = (f >> 3) & 3, j = f & 7;
  const size_t base = ((((size_t)d * 2 + kf) * 4 + lg) * 64) * 8 + j;
  #pragma unroll
  for (int q = 0; q < 4; ++q) {
    f32x4 v = *(const f32x4*)(bw + (size_t)d * 4096 + f * 64 + e0 + q * 4);
    #pragma unroll
    for (int r = 0; r < 4; ++r)
      bwT[base + (size_t)(e0 + q * 4 + r) * 8] = bfbits(v[r]);
  }
}

// ---------------- K0b (fallback when !FAST): plain maxx ----------------
__global__ void k_maxx(const float* __restrict__ x, float* __restrict__ bmax) {
  const int t = threadIdx.x;
  const float* px = x + (size_t)blockIdx.x * 8192;
  float m = 0.f;
  #pragma unroll 4
  for (int i = t; i < 8192; i += 256) m = fmaxf(m, px[i]);
  #pragma unroll
  for (int off = 32; off > 0; off >>= 1) m = fmaxf(m, __shfl_down(m, off, 64));
  __shared__ float red[4];
  if ((t & 63) == 0) red[t >> 6] = m;
  __syncthreads();
  if (t == 0) bmax[blockIdx.x] = fmaxf(fmaxf(red[0], red[1]), fmaxf(red[2], red[3]));
}

// ---------------- K1: breakpoints + effective-K flags + threshold table ----------------
__global__ void k_bp(const float* __restrict__ bmin, const float* __restrict__ draw,
                     const float* __restrict__ bmax, float* __restrict__ obp,
                     int* __restrict__ fdv, int* __restrict__ fcutc,
                     float* __restrict__ thrT) {
  const int d = threadIdx.x;  // 256 threads, one per d
  __shared__ float drawS[ND * NKBP];   // 63 KB, coalesced stage
  __shared__ float mred[256];
  __shared__ int fds[256];
  mred[d] = bmax[d];
  for (int i = d; i < ND * NKBP; i += 256) drawS[i] = draw[i];
  __syncthreads();
  for (int s = 128; s > 0; s >>= 1) {
    if (d < s) mred[d] = fmaxf(mred[d], mred[d + s]);
    __syncthreads();
  }
  const float maxx = mred[0];
  float a = bmin[d];
  int cnt = 0;
  if (thrT) thrT[d * 64] = 0.0f;
  for (int j = 0; j < NKBP; ++j) {
    float r = drawS[d * NKBP + j];
    a += fmaxf(r, 0.f) + log1pf(expf(-fabsf(r)));
    obp[d * NKBP + j] = a;
    if (thrT) thrT[d * 64 + 1 + j] = a;
    cnt += (a < maxx) ? 1 : 0;
  }
  const int Fd = 1 + cnt;
  fdv[d] = Fd;
  fds[d] = Fd;
  __syncthreads();
  if (d < NSPLIT) {
    int mx = 0;
    for (int k = 0; k < 64; ++k) mx = max(mx, fds[d * 64 + k]);
    fcutc[d] = (mx > 32) ? 2 : 1;
  }
}

// ---------------- K2: W2 (fragment-native blocked layout) + cbias partials ----------------
__global__ __launch_bounds__(256, 2) void k_w2(
    const float* __restrict__ bw, const float* __restrict__ pw,
    const float* __restrict__ bb, const int* __restrict__ fcutc,
    unsigned short* __restrict__ w2f, float* __restrict__ cb_part) {
  const int d = blockIdx.x;
  const int t = threadIdx.x;
  const int l = t & 63, w = t >> 6;
  const int lr = l & 15, lg = l >> 4;
  const int nkf = fcutc[d >> 6];   // 1 or 2
  __shared__ unsigned short pwS[256 * 72];
  __shared__ unsigned short bwS[64 * 72];
  __shared__ float bbS[64];

  {
    const int rr = t >> 4, e0 = (t & 15) * 4;
    #pragma unroll
    for (int it = 0; it < 16; ++it) {
      const int n = it * 16 + rr;
      f32x4 v = *(const f32x4*)(pw + (size_t)n * NDE + d * 64 + e0);
      short4_t s;
      s[0] = (short)bfbits(v[0]); s[1] = (short)bfbits(v[1]);
      s[2] = (short)bfbits(v[2]); s[3] = (short)bfbits(v[3]);
      *(short4_t*)(pwS + n * 72 + e0) = s;
    }
    const int itmax = (nkf == 2) ? 4 : 2;
    for (int it = 0; it < itmax; ++it) {
      const int f = it * 16 + rr;
      f32x4 v = *(const f32x4*)(bw + (size_t)d * 4096 + f * 64 + e0);
      short4_t s;
      s[0] = (short)bfbits(v[0]); s[1] = (short)bfbits(v[1]);
      s[2] = (short)bfbits(v[2]); s[3] = (short)bfbits(v[3]);
      *(short4_t*)(bwS + f * 72 + e0) = s;
    }
    if (t < 64) bbS[t] = bb[(size_t)d * 64 + t];
  }
  __syncthreads();

  f32x4 acc[4][4];
  #pragma unroll
  for (int mi = 0; mi < 4; ++mi)
    #pragma unroll
    for (int ni = 0; ni < 4; ++ni) acc[mi][ni] = (f32x4){0.f, 0.f, 0.f, 0.f};

  const int nimax = (nkf == 2) ? 4 : 2;
  for (int kf = 0; kf < nkf; ++kf) {
    short8_t afr[4], bfr[4];
    #pragma unroll
    for (int mi = 0; mi < 4; ++mi) {
      const int n = w * 64 + mi * 16 + lr;
      afr[mi] = *(const short8_t*)(pwS + n * 72 + kf * 32 + lg * 8);
    }
    for (int ni = 0; ni < nimax; ++ni) {
      const int f = ni * 16 + lr;
      bfr[ni] = *(const short8_t*)(bwS + f * 72 + kf * 32 + lg * 8);
    }
    for (int ni = 0; ni < nimax; ++ni)
      #pragma unroll
      for (int mi = 0; mi < 4; ++mi)
        acc[mi][ni] = __builtin_amdgcn_mfma_f32_16x16x32_bf16(afr[mi], bfr[ni], acc[mi][ni], 0, 0, 0);
  }

  #pragma unroll
  for (int mi = 0; mi < 4; ++mi)
    for (int ni = 0; ni < nimax; ++ni) {
      const int kf_s = ni >> 1;
      const int lgp  = (ni * 2 + (lr >> 3)) & 3;
      const int jj   = lr & 7;
      const int nb   = w * 64 + mi * 16 + lg * 4;
      const size_t base = (((size_t)d * 2 + kf_s) * 4 + lgp) * 256;
      #pragma unroll
      for (int r = 0; r < 4; ++r)
        w2f[(base + (nb + r)) * 8 + jj] = bfbits(acc[mi][ni][r]);
    }

  {
    float cacc = 0.f;
    #pragma unroll 8
    for (int e = 0; e < 64; ++e) cacc += bf2f(pwS[t * 72 + e]) * bbS[e];
    cb_part[(size_t)d * 256 + t] = cacc;
  }
}

// ---------------- K2r: cbias[n] = sum_d cb_part[d][n] ----------------
__global__ void k_cbr(const float* __restrict__ cb_part, float* __restrict__ c) {
  const int t = threadIdx.x;
  float a0 = 0.f, a1 = 0.f, a2 = 0.f, a3 = 0.f;
  for (int d = 0; d < ND; d += 4) {
    a0 += cb_part[(size_t)(d + 0) * 256 + t];
    a1 += cb_part[(size_t)(d + 1) * 256 + t];
    a2 += cb_part[(size_t)(d + 2) * 256 + t];
    a3 += cb_part[(size_t)(d + 3) * 256 + t];
  }
  c[t] = (a0 + a1) + (a2 + a3);
}

// ---------------- K3: projection GEMM partials (r13 structure) ----------------
template<bool KF1>
__device__ __forceinline__ void proj_kloop(
    const unsigned short* const (&bbase)[4], const float* const (&xrow)[2],
    const float* thrS_lg, bool lg0, f32x4 (&acc)[2][4]) {
  for (int c = 0; c < 8; ++c) {
    f32x4 xqa[2], xqb[2];
    #pragma unroll
    for (int mi = 0; mi < 2; ++mi) {
      xqa[mi] = *(const f32x4*)(xrow[mi] + c * 8);
      xqb[mi] = *(const f32x4*)(xrow[mi] + c * 8 + 4);
    }
    #pragma unroll
    for (int dd = 0; dd < 8; ++dd) {
      const int dl = c * 8 + dd;
      short8_t bfr0[4], bfr1[4];
      #pragma unroll
      for (int ni = 0; ni < 4; ++ni)
        bfr0[ni] = *(const short8_t*)(bbase[ni] + (size_t)dl * 16384);
      if (KF1) {
        #pragma unroll
        for (int ni = 0; ni < 4; ++ni)
          bfr1[ni] = *(const short8_t*)(bbase[ni] + (size_t)dl * 16384 + 8192);
      }
      const float* tp = thrS_lg + dl * 64;
      f32x4 ta = *(const f32x4*)(tp);
      f32x4 tb = *(const f32x4*)(tp + 4);
      short8_t afr0[2], afr1[2];
      #pragma unroll
      for (int mi = 0; mi < 2; ++mi) {
        const float xv = (dd < 4) ? xqa[mi][dd & 3] : xqb[mi][dd & 3];
        short8_t A0;
        A0[0] = (short)bfbits(lg0 ? xv : fmaxf(xv - ta[0], 0.f));
        A0[1] = (short)bfbits(fmaxf(xv - ta[1], 0.f));
        A0[2] = (short)bfbits(fmaxf(xv - ta[2], 0.f));
        A0[3] = (short)bfbits(fmaxf(xv - ta[3], 0.f));
        A0[4] = (short)bfbits(fmaxf(xv - tb[0], 0.f));
        A0[5] = (short)bfbits(fmaxf(xv - tb[1], 0.f));
        A0[6] = (short)bfbits(fmaxf(xv - tb[2], 0.f));
        A0[7] = (short)bfbits(fmaxf(xv - tb[3], 0.f));
        afr0[mi] = A0;
      }
      if (KF1) {
        f32x4 tc = *(const f32x4*)(tp + 32);
        f32x4 td = *(const f32x4*)(tp + 36);
        #pragma unroll
        for (int mi = 0; mi < 2; ++mi) {
          const float xv = (dd < 4) ? xqa[mi][dd & 3] : xqb[mi][dd & 3];
          short8_t A1;
          A1[0] = (short)bfbits(fmaxf(xv - tc[0], 0.f));
          A1[1] = (short)bfbits(fmaxf(xv - tc[1], 0.f));
          A1[2] = (short)bfbits(fmaxf(xv - tc[2], 0.f));
          A1[3] = (short)bfbits(fmaxf(xv - tc[3], 0.f));
          A1[4] = (short)bfbits(fmaxf(xv - td[0], 0.f));
          A1[5] = (short)bfbits(fmaxf(xv - td[1], 0.f));
          A1[6] = (short)bfbits(fmaxf(xv - td[2], 0.f));
          A1[7] = (short)bfbits(fmaxf(xv - td[3], 0.f));
          afr1[mi] = A1;
        }
      }
      #pragma unroll
      for (int mi = 0; mi < 2; ++mi)
        #pragma unroll
        for (int ni = 0; ni < 4; ++ni)
          acc[mi][ni] = __builtin_amdgcn_mfma_f32_16x16x32_bf16(afr0[mi], bfr0[ni], acc[mi][ni], 0, 0, 0);
      if (KF1) {
        #pragma unroll
        for (int mi = 0; mi < 2; ++mi)
          #pragma unroll
          for (int ni = 0; ni < 4; ++ni)
            acc[mi][ni] = __builtin_amdgcn_mfma_f32_16x16x32_bf16(afr1[mi], bfr1[ni], acc[mi][ni], 0, 0, 0);
      }
    }
  }
}

__global__ __launch_bounds__(256, 3) void k_proj(
    const unsigned short* __restrict__ w2f, const float* __restrict__ bp,
    const float* __restrict__ x, const int* __restrict__ fcutc,
    float* __restrict__ pbuf) {
  const int t = threadIdx.x;
  const int l = t & 63, w = t >> 6;
  const int lr = l & 15, lg = l >> 4;
  const int bM = blockIdx.x * 128;
  const int bN = blockIdx.y * 64;
  const int d0 = blockIdx.z * 64;
  __shared__ float thrS[64 * 64];

  for (int i = t; i < 4096; i += 256) {
    const int dl = i >> 6, f = i & 63;
    thrS[i] = (f >= 1) ? bp[(size_t)(d0 + dl) * NKBP + f - 1] : 0.0f;
  }
  __syncthreads();

  f32x4 acc[2][4];
  #pragma unroll
  for (int mi = 0; mi < 2; ++mi)
    #pragma unroll
    for (int ni = 0; ni < 4; ++ni) acc[mi][ni] = (f32x4){0.f, 0.f, 0.f, 0.f};

  const bool lg0 = (lg == 0);
  const unsigned short* bbase[4];
  #pragma unroll
  for (int ni = 0; ni < 4; ++ni)
    bbase[ni] = w2f + (size_t)d0 * 16384 + (size_t)(bN + ni * 16 + lr) * 8 + (size_t)lg * 2048;
  const float* xrow[2];
  #pragma unroll
  for (int mi = 0; mi < 2; ++mi)
    xrow[mi] = x + (size_t)(bM + w * 32 + mi * 16 + lr) * ND + d0;

  const int nkf = fcutc[blockIdx.z];
  if (nkf == 1) proj_kloop<false>(bbase, xrow, thrS + lg * 8, lg0, acc);
  else          proj_kloop<true >(bbase, xrow, thrS + lg * 8, lg0, acc);

  float* pp = pbuf + (size_t)blockIdx.z * ((size_t)NB * ND);
  #pragma unroll
  for (int mi = 0; mi < 2; ++mi)
    #pragma unroll
    for (int ni = 0; ni < 4; ++ni) {
      const int col = bN + ni * 16 + lr;
      const int rowb = bM + w * 32 + mi * 16 + lg * 4;
      #pragma unroll
      for (int r = 0; r < 4; ++r)
        pp[(size_t)(rowb + r) * ND + col] = acc[mi][ni][r];
    }
}

// ---------------- K4: combine partials -> x_emb ----------------
__global__ void k_comb(const float* __restrict__ x, const float* __restrict__ pbuf,
                       const float* __restrict__ cbuf, const float* __restrict__ pb,
                       float* __restrict__ xe) {
  const size_t i = ((size_t)blockIdx.x * 256 + threadIdx.x) * 4;
  const int n = (int)(i & 255);
  f32x4 s = *(const f32x4*)(pbuf + i);
  #pragma unroll
  for (int p = 1; p < NSPLIT; ++p)
    s += *(const f32x4*)(pbuf + (size_t)p * 2097152 + i);
  f32x4 cv = *(const f32x4*)(cbuf + n);
  f32x4 pv = *(const f32x4*)(pb + n);
  f32x4 xv = *(const f32x4*)(x + i);
  *(f32x4*)(xe + i) = xv + 0.1f * (s + cv + pv);
}

// ---------------- K5 (fast): 32 rows x 4 d per block; per-wave d; 1KB-burst stores ----------------
__global__ __launch_bounds__(256, 3) void k_emb3(
    const float* __restrict__ x, const unsigned short* __restrict__ bwT,
    const float* __restrict__ bb, const float* __restrict__ thrT,
    const int* __restrict__ fdv, float* __restrict__ oe) {
  const int dc = blockIdx.x;          // d-chunk of 4
  const int b0 = blockIdx.y * 32;
  const int t = threadIdx.x;
  const int l = t & 63, w = t >> 6;   // wave w owns d = dc*4 + w
  const int lr = l & 15, lg = l >> 4;
  const int d = dc * 4 + w;
  __shared__ float slab[32 * 260];    // 33.3 KB

  const int nkf = (fdv[d] > 32) ? 2 : 1;

  float xg[2];
  xg[0] = x[(size_t)(b0 + lr) * ND + d];
  xg[1] = x[(size_t)(b0 + 16 + lr) * ND + d];

  f32x4 ta = *(const f32x4*)(thrT + d * 64 + lg * 8);
  f32x4 tb = *(const f32x4*)(thrT + d * 64 + lg * 8 + 4);
  const bool lg0 = (lg == 0);

  float bbv[4];
  #pragma unroll
  for (int ni = 0; ni < 4; ++ni) bbv[ni] = bb[(size_t)d * 64 + ni * 16 + lr];

  const unsigned short* bk0 = bwT + ((size_t)d * 8 + lg) * 512;
  short8_t bfr0[4];
  #pragma unroll
  for (int ni = 0; ni < 4; ++ni)
    bfr0[ni] = *(const short8_t*)(bk0 + (ni * 16 + lr) * 8);

  short8_t afr0[2];
  #pragma unroll
  for (int mi = 0; mi < 2; ++mi) {
    const float xv = xg[mi];
    short8_t A0;
    A0[0] = (short)bfbits(lg0 ? xv : fmaxf(xv - ta[0], 0.f));
    A0[1] = (short)bfbits(fmaxf(xv - ta[1], 0.f));
    A0[2] = (short)bfbits(fmaxf(xv - ta[2], 0.f));
    A0[3] = (short)bfbits(fmaxf(xv - ta[3], 0.f));
    A0[4] = (short)bfbits(fmaxf(xv - tb[0], 0.f));
    A0[5] = (short)bfbits(fmaxf(xv - tb[1], 0.f));
    A0[6] = (short)bfbits(fmaxf(xv - tb[2], 0.f));
    A0[7] = (short)bfbits(fmaxf(xv - tb[3], 0.f));
    afr0[mi] = A0;
  }

  f32x4 acc[2][4];
  #pragma unroll
  for (int mi = 0; mi < 2; ++mi)
    #pragma unroll
    for (int ni = 0; ni < 4; ++ni) acc[mi][ni] = (f32x4){0.f, 0.f, 0.f, 0.f};
  #pragma unroll
  for (int mi = 0; mi < 2; ++mi)
    #pragma unroll
    for (int ni = 0; ni < 4; ++ni)
      acc[mi][ni] = __builtin_amdgcn_mfma_f32_16x16x32_bf16(afr0[mi], bfr0[ni], acc[mi][ni], 0, 0, 0);

  if (nkf == 2) {
    f32x4 tc = *(const f32x4*)(thrT + d * 64 + 32 + lg * 8);
    f32x4 td = *(const f32x4*)(thrT + d * 64 + 36 + lg * 8);
    const unsigned short* bk1 = bwT + ((size_t)d * 8 + 4 + lg) * 512;
    short8_t afr1[2], bfr1[4];
    #pragma unroll
    for (int ni = 0; ni < 4; ++ni)
      bfr1[ni] = *(const short8_t*)(bk1 + (ni * 16 + lr) * 8);
    #pragma unroll
    for (int mi = 0; mi < 2; ++mi) {
      const float xv = xg[mi];
      short8_t A1;
      A1[0] = (short)bfbits(fmaxf(xv - tc[0], 0.f));
      A1[1] = (short)bfbits(fmaxf(xv - tc[1], 0.f));
      A1[2] = (short)bfbits(fmaxf(xv - tc[2], 0.f));
      A1[3] = (short)bfbits(fmaxf(xv - tc[3], 0.f));
      A1[4] = (short)bfbits(fmaxf(xv - td[0], 0.f));
      A1[5] = (short)bfbits(fmaxf(xv - td[1], 0.f));
      A1[6] = (short)bfbits(fmaxf(xv - td[2], 0.f));
      A1[7] = (short)bfbits(fmaxf(xv - td[3], 0.f));
      afr1[mi] = A1;
    }
    #pragma unroll
    for (int mi = 0; mi < 2; ++mi)
      #pragma unroll
      for (int ni = 0; ni < 4; ++ni)
        acc[mi][ni] = __builtin_amdgcn_mfma_f32_16x16x32_bf16(afr1[mi], bfr1[ni], acc[mi][ni], 0, 0, 0);
  }

  #pragma unroll
  for (int ni = 0; ni < 4; ++ni)
    #pragma unroll
    for (int mi = 0; mi < 2; ++mi)
      #pragma unroll
      for (int r = 0; r < 4; ++r)
        slab[(mi * 16 + lg * 4 + r) * 260 + w * 64 + ni * 16 + lr] = acc[mi][ni][r] + bbv[ni];
  __syncthreads();

  #pragma unroll
  for (int p = 0; p < 8; ++p) {
    const int row = w * 8 + p;
    f32x4 v = *(const f32x4*)(slab + row * 260 + l * 4);
    *(f32x4*)(oe + (size_t)(b0 + row) * NDE + dc * 256 + l * 4) = v;
  }
}

// ---------------- K5 (fallback): round-8 structure, d-fastest grid ----------------
__global__ __launch_bounds__(256, 2) void k_emb_fb(
    const float* __restrict__ x, const float* __restrict__ bw,
    const float* __restrict__ bb, const float* __restrict__ bp,
    const int* __restrict__ fdv, float* __restrict__ oe) {
  const int d = blockIdx.x;
  const int b0 = blockIdx.y * 256;
  const int t = threadIdx.x;
  const int l = t & 63, w = t >> 6;
  const int lr = l & 15, lg = l >> 4;
  __shared__ unsigned short btS[64 * 72];
  __shared__ float thrF[64];
  __shared__ float bbS[64];
  __shared__ float cS[4 * 64 * 68];

  const int nkf = (fdv[d] > 32) ? 2 : 1;
  float xg[4];
  #pragma unroll
  for (int mi = 0; mi < 4; ++mi)
    xg[mi] = x[(size_t)(b0 + w * 64 + mi * 16 + lr) * ND + d];

  if (t < 64) thrF[t] = (t >= 1) ? bp[(size_t)d * NKBP + t - 1] : 0.0f;
  else if (t < 128) bbS[t - 64] = bb[(size_t)d * 64 + (t - 64)];
  {
    const float* bwd = bw + (size_t)d * 4096;
    const int f = t >> 2, e0 = (t & 3) * 16;
    #pragma unroll
    for (int q = 0; q < 4; ++q) {
      f32x4 v = *(const f32x4*)(bwd + f * 64 + e0 + q * 4);
      #pragma unroll
      for (int r = 0; r < 4; ++r) {
        const int e = e0 + q * 4 + r;
        btS[e * 72 + f] = bfbits(v[r]);
      }
    }
  }
  __syncthreads();

  f32x4 ta = *(const f32x4*)(thrF + lg * 8);
  f32x4 tb = *(const f32x4*)(thrF + lg * 8 + 4);
  const bool lg0 = (lg == 0);

  short8_t afr0[4];
  #pragma unroll
  for (int mi = 0; mi < 4; ++mi) {
    const float xv = xg[mi];
    short8_t A0;
    A0[0] = (short)bfbits(lg0 ? xv : fmaxf(xv - ta[0], 0.f));
    A0[1] = (short)bfbits(fmaxf(xv - ta[1], 0.f));
    A0[2] = (short)bfbits(fmaxf(xv - ta[2], 0.f));
    A0[3] = (short)bfbits(fmaxf(xv - ta[3], 0.f));
    A0[4] = (short)bfbits(fmaxf(xv - tb[0], 0.f));
    A0[5] = (short)bfbits(fmaxf(xv - tb[1], 0.f));
    A0[6] = (short)bfbits(fmaxf(xv - tb[2], 0.f));
    A0[7] = (short)bfbits(fmaxf(xv - tb[3], 0.f));
    afr0[mi] = A0;
  }
  short8_t bfr0[4];
  #pragma unroll
  for (int ni = 0; ni < 4; ++ni) {
    const int e = ni * 16 + lr;
    bfr0[ni] = *(const short8_t*)(btS + e * 72 + lg * 8);
  }
  f32x4 acc[4][4];
  #pragma unroll
  for (int mi = 0; mi < 4; ++mi)
    #pragma unroll
    for (int ni = 0; ni < 4; ++ni) acc[mi][ni] = (f32x4){0.f, 0.f, 0.f, 0.f};
  #pragma unroll
  for (int mi = 0; mi < 4; ++mi)
    #pragma unroll
    for (int ni = 0; ni < 4; ++ni)
      acc[mi][ni] = __builtin_amdgcn_mfma_f32_16x16x32_bf16(afr0[mi], bfr0[ni], acc[mi][ni], 0, 0, 0);

  if (nkf == 2) {
    f32x4 tc = *(const f32x4*)(thrF + 32 + lg * 8);
    f32x4 td = *(const f32x4*)(thrF + 36 + lg * 8);
    short8_t afr1[4], bfr1[4];
    #pragma unroll
    for (int mi = 0; mi < 4; ++mi) {
      const float xv = xg[mi];
      short8_t A1;
      A1[0] = (short)bfbits(fmaxf(xv - tc[0], 0.f));
      A1[1] = (short)bfbits(fmaxf(xv - tc[1], 0.f));
      A1[2] = (short)bfbits(fmaxf(xv - tc[2], 0.f));
      A1[3] = (short)bfbits(fmaxf(xv - tc[3], 0.f));
      A1[4] = (short)bfbits(fmaxf(xv - td[0], 0.f));
      A1[5] = (short)bfbits(fmaxf(xv - td[1], 0.f));
      A1[6] = (short)bfbits(fmaxf(xv - td[2], 0.f));
      A1[7] = (short)bfbits(fmaxf(xv - td[3], 0.f));
      afr1[mi] = A1;
    }
    #pragma unroll
    for (int ni = 0; ni < 4; ++ni) {
      const int e = ni * 16 + lr;
      bfr1[ni] = *(const short8_t*)(btS + e * 72 + 32 + lg * 8);
    }
    #pragma unroll
    for (int mi = 0; mi < 4; ++mi)
      #pragma unroll
      for (int ni = 0; ni < 4; ++ni)
        acc[mi][ni] = __builtin_amdgcn_mfma_f32_16x16x32_bf16(afr1[mi], bfr1[ni], acc[mi][ni], 0, 0, 0);
  }

  #pragma unroll
  for (int ni = 0; ni < 4; ++ni) {
    const float bbv = bbS[ni * 16 + lr];
    #pragma unroll
    for (int mi = 0; mi < 4; ++mi) {
      const int rw = mi * 16 + lg * 4;
      #pragma unroll
      for (int r = 0; r < 4; ++r)
        cS[w * 4352 + (rw + r) * 68 + ni * 16 + lr] = acc[mi][ni][r] + bbv;
    }
  }
  __syncthreads();

  const int rsub = t >> 4;
  const int c4 = (t & 15) * 4;
  #pragma unroll
  for (int p = 0; p < 16; ++p) {
    const int row = p * 16 + rsub;
    const int wsrc = row >> 6, wr = row & 63;
    f32x4 v = *(const f32x4*)(cS + wsrc * 4352 + wr * 68 + c4);
    *(f32x4*)(oe + (size_t)(b0 + row) * NDE + d * 64 + c4) = v;
  }
}

extern "C" void kernel_launch(void* const* d_in, const int* in_sizes, int n_in,
                              void* d_out, int out_size, void* d_ws, size_t ws_size,
                              hipStream_t stream) {
  const float* x    = (const float*)d_in[0];
  const float* bw   = (const float*)d_in[1];
  const float* bb   = (const float*)d_in[2];
  const float* pw   = (const float*)d_in[3];
  const float* pb   = (const float*)d_in[4];
  const float* bmin = (const float*)d_in[5];
  const float* draw = (const float*)d_in[6];

  float* out    = (float*)d_out;
  float* out_x  = out;                          // [8192*256]
  float* out_e  = out + (size_t)NB * ND;        // [8192*256*64]
  float* out_bp = out_e + (size_t)NB * NDE;     // [256*63]

  unsigned short* w2f = (unsigned short*)out_x; // 8.39 MB, overwritten by k_comb
  float* cbuf    = out_e;                            // 256 f32
  float* pbuf    = out_e + 65536;                    // NSPLIT * 2097152 f32 = 33.5 MB
  float* cb_part = out_e + 65536 + NSPLIT * 2097152; // 256 KB

  // d_ws layout: bmax[256] fdv[256] fcutc[8] | thrT[16384] | bwT[1M ushort]
  float* wsf  = (float*)d_ws;
  float* bmax = wsf;
  int*   fdv  = (int*)wsf + 256;
  int*   fcutc= (int*)wsf + 512;
  float* thrT = wsf + 768;
  unsigned short* bwT = (unsigned short*)(wsf + 768 + 16384);
  const bool FAST = ws_size >= (size_t)(768 + 16384) * 4 + (size_t)2097152 * 2 + 256;

  if (FAST)
    k_mp <<<dim3(256),         dim3(256), 0, stream>>>(x, bw, bmax, bwT);
  else
    k_maxx<<<dim3(256),        dim3(256), 0, stream>>>(x, bmax);
  k_bp  <<<dim3(1),            dim3(256), 0, stream>>>(bmin, draw, bmax, out_bp, fdv, fcutc,
                                                       FAST ? thrT : (float*)nullptr);
  k_w2  <<<dim3(256),          dim3(256), 0, stream>>>(bw, pw, bb, fcutc, w2f, cb_part);
  k_cbr <<<dim3(1),            dim3(256), 0, stream>>>(cb_part, cbuf);
  k_proj<<<dim3(64, 4, NSPLIT),dim3(256), 0, stream>>>(w2f, out_bp, x, fcutc, pbuf);
  k_comb<<<dim3(2048),         dim3(256), 0, stream>>>(x, pbuf, cbuf, pb, out_x);
  if (FAST)
    k_emb3<<<dim3(64, 256),    dim3(256), 0, stream>>>(x, bwT, bb, thrT, fdv, out_e);
  else
    k_emb_fb<<<dim3(256, 32),  dim3(256), 0, stream>>>(x, bw, bb, out_bp, fdv, out_e);
}